// Round 5
// baseline (860.933 us; speedup 1.0000x reference)
//
#include <hip/hip_runtime.h>

// Sinkhorn OT, scaling form, SINGLE persistent kernel, one exchange/iter:
//   K = exp(-C/eps); s0 = 1
//   iter t: r_t[m] = inv/(K[m,:]*s_{t-1})            (block-local, owns rows)
//           partial_b[c] = sum_{m in block} K[m][c]*r_t[m]   (block-local)
//           acc_t[c] = sum_b partial_b[c]  (atomicAdd all-reduce at L3)
//           s_t[c] = inv/acc_t[c]
//   P = diag(r_40) K diag(s_40); dist_b = sum(P .* C)
// B=4, M=N=1024, fp32. Output: dist (B floats) then P (B*M*N floats).
//
// R4 post-mortem: 80 serial exchanges x ~3.8us. R5: row-ownership lets each
// block compute its column-partials itself -> 41 exchanges (40 iters + init).
// No KT, no transpose, no K in global, no zero kernel: K lives only in LDS.
// Sync is pure tagged dataflow (poison-safe equality tags; 40 distinct acc
// buffers so no reuse hazards). atomicAdds execute at the coherence point;
// __syncthreads' vmcnt(0) drain orders them before the arrival store.

#define MN    1024
#define EPS_INV 10.0f
#define ITERS 40
#define BPB   64   // blocks per batch
#define ROWS  16   // rows per block

__device__ __forceinline__ float wave_reduce(float v) {
#pragma unroll
    for (int off = 32; off; off >>= 1) v += __shfl_xor(v, off, 64);
    return v;
}

__device__ __forceinline__ float dot4(float4 a, float4 b) {
    return a.x * b.x + a.y * b.y + a.z * b.z + a.w * b.w;
}

__device__ __forceinline__ unsigned ld_tag(const unsigned* p) {
    return __hip_atomic_load(p, __ATOMIC_RELAXED, __HIP_MEMORY_SCOPE_AGENT);
}

// grid: B*64 blocks (1/CU), 256 threads (4 waves)
__global__ __launch_bounds__(256, 1) void sink_all(
        const float* __restrict__ C, float* __restrict__ acc,
        unsigned* __restrict__ arr, unsigned long long* __restrict__ dpart,
        float* __restrict__ P, float* __restrict__ dist) {
    __shared__ float ldsK[ROWS * MN];  // 64 KB: this block's K strip
    __shared__ float vlds[MN];         // staged s vector
    __shared__ float rbuf[ROWS];       // this block's r values
    __shared__ float wsum[4];

    const int blk   = blockIdx.x;
    const int batch = blk / BPB;
    const int bb    = blk % BPB;       // block-in-batch
    const int tid   = threadIdx.x;
    const int wid   = tid >> 6;
    const int lane  = tid & 63;
    const int row0  = blk * ROWS;      // == batch*MN + bb*ROWS

    // ---- build K strip in LDS directly from C (coalesced float4 + expf) ----
    {
        const float4* c4g = (const float4*)(C + (size_t)row0 * MN);
        float4* k4l = (float4*)ldsK;
        for (int i = tid; i < ROWS * MN / 4; i += 256) {
            float4 c = c4g[i];
            float4 k;
            k.x = expf(-EPS_INV * c.x);
            k.y = expf(-EPS_INV * c.y);
            k.z = expf(-EPS_INV * c.z);
            k.w = expf(-EPS_INV * c.w);
            k4l[i] = k;
        }
    }

    // ---- zero own 16-column slice of all 40 acc buffers (sc1 stores) ----
    float* accB = acc + (size_t)batch * ITERS * MN;
    for (int i = tid; i < ITERS * 16; i += 256) {
        int t = i >> 4, c = (i & 15) + bb * 16;
        __hip_atomic_store(accB + (size_t)t * MN + c, 0.0f,
                           __ATOMIC_RELAXED, __HIP_MEMORY_SCOPE_AGENT);
    }
    __syncthreads();  // drains every wave's vmcnt -> zeros + LDS build done

    unsigned* arrB = arr + (size_t)batch * (ITERS + 1) * 64;
    if (tid == 0)
        __hip_atomic_store(arrB + bb, 1u, __ATOMIC_RELAXED, __HIP_MEMORY_SCOPE_AGENT);
    while (!__all(ld_tag(arrB + lane) == 1u)) __builtin_amdgcn_s_sleep(1);
    __syncthreads();

    const float inv = 1.0f / (float)MN;
    float rv[4];

    for (int t = 1; t <= ITERS; ++t) {
        // ---- r-phase: r[m] = inv / (K[m,:] . s_{t-1}); s_0 == 1 ----
        float4 v0, v1, v2, v3;
        if (t == 1) {
            v0 = v1 = v2 = v3 = make_float4(1.f, 1.f, 1.f, 1.f);
        } else {
            const float4* sv4 = (const float4*)vlds;
            v0 = sv4[lane]; v1 = sv4[64 + lane];
            v2 = sv4[128 + lane]; v3 = sv4[192 + lane];
        }
#pragma unroll
        for (int j = 0; j < 4; ++j) {
            const float4* l4 = (const float4*)(ldsK + (wid * 4 + j) * MN);
            float a = dot4(l4[lane], v0) + dot4(l4[64 + lane], v1)
                    + dot4(l4[128 + lane], v2) + dot4(l4[192 + lane], v3);
            a = wave_reduce(a);
            rv[j] = inv / a;
            if (lane == 0) rbuf[wid * 4 + j] = rv[j];
        }
        __syncthreads();  // rbuf ready; everyone done reading vlds

        // ---- partial[c] = sum_m K[m][c]*r[m]; thread owns cols 4*tid.. ----
        const int c0 = tid * 4;
        float4 facc = make_float4(0.f, 0.f, 0.f, 0.f);
#pragma unroll
        for (int m = 0; m < ROWS; ++m) {
            float4 k4 = *(const float4*)(ldsK + m * MN + c0);
            float rm = rbuf[m];  // LDS broadcast
            facc.x += k4.x * rm; facc.y += k4.y * rm;
            facc.z += k4.z * rm; facc.w += k4.w * rm;
        }
        float* accT = accB + (size_t)(t - 1) * MN;
        atomicAdd(accT + c0 + 0, facc.x);
        atomicAdd(accT + c0 + 1, facc.y);
        atomicAdd(accT + c0 + 2, facc.z);
        atomicAdd(accT + c0 + 3, facc.w);
        __syncthreads();  // vmcnt(0) in every wave: all adds committed

        // ---- arrival + poll (tagged, poison-safe) ----
        if (tid == 0)
            __hip_atomic_store(arrB + (size_t)t * 64 + bb, (unsigned)t,
                               __ATOMIC_RELAXED, __HIP_MEMORY_SCOPE_AGENT);
        {
            const unsigned* at = arrB + (size_t)t * 64;
            while (!__all(ld_tag(at + lane) == (unsigned)t))
                __builtin_amdgcn_s_sleep(1);
        }
        // ---- stage s_t = inv / acc_t into vlds ----
        for (int i = tid; i < MN; i += 256) {
            float a = __hip_atomic_load(accT + i, __ATOMIC_RELAXED,
                                        __HIP_MEMORY_SCOPE_AGENT);
            vlds[i] = inv / a;
        }
        __syncthreads();
    }

    // ---- finalize: P[row,:] = r[m]*K[m,:]*s ; dist via tagged partials ----
    float4 sv[4];
    {
        const float4* sv4 = (const float4*)vlds;  // s_40
        sv[0] = sv4[lane]; sv[1] = sv4[64 + lane];
        sv[2] = sv4[128 + lane]; sv[3] = sv4[192 + lane];
    }
    float part = 0.f;
#pragma unroll
    for (int j = 0; j < 4; ++j) {
        const int row = row0 + wid * 4 + j;
        const float4* l4 = (const float4*)(ldsK + (wid * 4 + j) * MN);
        const float4* c4 = (const float4*)(C + (size_t)row * MN);
        float4*       p4 = (float4*)(P + (size_t)row * MN);
        const float rj = rv[j];
#pragma unroll
        for (int c = 0; c < 4; ++c) {
            float4 k  = l4[c * 64 + lane];
            float4 cc = c4[c * 64 + lane];
            float4 pp;
            pp.x = rj * k.x * sv[c].x;
            pp.y = rj * k.y * sv[c].y;
            pp.z = rj * k.z * sv[c].z;
            pp.w = rj * k.w * sv[c].w;
            p4[c * 64 + lane] = pp;
            part += dot4(pp, cc);
        }
    }
    part = wave_reduce(part);
    if (lane == 0) wsum[wid] = part;
    __syncthreads();
    if (tid == 0) {
        float tot = wsum[0] + wsum[1] + wsum[2] + wsum[3];
        unsigned long long w = (0x5151ULL << 32) |
                               (unsigned long long)__float_as_uint(tot);
        __hip_atomic_store(dpart + blk, w, __ATOMIC_RELAXED, __HIP_MEMORY_SCOPE_AGENT);
    }
    // batch leader (block bb==0), wave 0: sum the 64 tagged partials
    if (bb == 0 && wid == 0) {
        unsigned long long w;
        for (;;) {
            w = __hip_atomic_load(dpart + (size_t)batch * 64 + lane,
                                  __ATOMIC_RELAXED, __HIP_MEMORY_SCOPE_AGENT);
            if (__all((unsigned)(w >> 32) == 0x5151u)) break;
            __builtin_amdgcn_s_sleep(1);
        }
        float v = wave_reduce(__uint_as_float((unsigned)w));
        if (lane == 0) dist[batch] = v;
    }
}

extern "C" void kernel_launch(void* const* d_in, const int* in_sizes, int n_in,
                              void* d_out, int out_size, void* d_ws, size_t ws_size,
                              hipStream_t stream) {
    const float* C = (const float*)d_in[0];
    const int B = in_sizes[0] / (MN * MN);  // 4

    // ws: acc [B*40*1024 f32] | dpart [B*64 u64] | arr [B*41*64 u32]
    float* acc = (float*)d_ws;
    unsigned long long* dpart = (unsigned long long*)(acc + (size_t)B * ITERS * MN);
    unsigned* arr = (unsigned*)(dpart + (size_t)B * 64);

    float* dist = (float*)d_out;       // (B,)
    float* P    = (float*)d_out + B;   // (B, MN, MN)

    sink_all<<<B * BPB, 256, 0, stream>>>(C, acc, arr, dpart, P, dist);
}

// Round 6
// 455.593 us; speedup vs baseline: 1.8897x; 1.8897x over previous
//
#include <hip/hip_runtime.h>

// Sinkhorn OT, scaling form, SINGLE persistent kernel, depth-2 tagged
// dataflow all-reduce (NO atomics, no fences, nothing to initialize):
//   K = exp(-C/eps); s0 = 1
//   iter t: r_t[m] = inv/(K[m,:].s_{t-1})              (block-local rows)
//           partial_bb[c] = sum_{m in bb} K[m][c]*r_t[m]  (block-local)
//           [hop A] publish partial (4KB) + tag; column owner bb reduces
//                   64 partials over its 16 cols -> s_t slice + tag
//           [hop B] all blocks read full s_t (4KB)
//   P = diag(r_40) K diag(s_40); dist_b = sum(P .* C)
// B=4, M=N=1024, fp32. Output: dist (B floats) then P (B*M*N floats).
//
// R5 post-mortem: atomicAdd all-reduce = 181 MB HBM RMW write-through +
// 64-way same-word serialization (861 us). R6 keeps the halved exchange
// count (40, not 80) but does the reduction as write-once sc1 dataflow.
// Tags are equality-checked (t), so 0xAA poison never false-fires; every
// (t,slot) is written exactly once -> no ABA, no zeroing, one dispatch.

#define MN      1024
#define EPS_INV 10.0f
#define ITERS   40
#define BPB     64   // blocks per batch
#define ROWS    16   // rows per block

__device__ __forceinline__ float wave_reduce(float v) {
#pragma unroll
    for (int off = 32; off; off >>= 1) v += __shfl_xor(v, off, 64);
    return v;
}

__device__ __forceinline__ float dot4(float4 a, float4 b) {
    return a.x * b.x + a.y * b.y + a.z * b.z + a.w * b.w;
}

__device__ __forceinline__ unsigned ld_tag(const unsigned* p) {
    return __hip_atomic_load(p, __ATOMIC_RELAXED, __HIP_MEMORY_SCOPE_AGENT);
}
__device__ __forceinline__ float ld_f(const float* p) {
    return __hip_atomic_load(p, __ATOMIC_RELAXED, __HIP_MEMORY_SCOPE_AGENT);
}
__device__ __forceinline__ void st_f(float* p, float v) {
    __hip_atomic_store(p, v, __ATOMIC_RELAXED, __HIP_MEMORY_SCOPE_AGENT);
}

// grid: B*64 blocks (1/CU), 256 threads (4 waves)
__global__ __launch_bounds__(256, 1) void sink_all(
        const float* __restrict__ C, float* __restrict__ part,
        float* __restrict__ svec_g, unsigned* __restrict__ arrA,
        unsigned* __restrict__ arrB, unsigned long long* __restrict__ dpart,
        float* __restrict__ P, float* __restrict__ dist) {
    __shared__ float ldsK[ROWS * MN];   // 64 KB K strip
    __shared__ float vlds[MN];          // staged s vector
    __shared__ float rbuf[ROWS];
    __shared__ float redsum[16][17];    // [col_local][producer_chunk], padded
    __shared__ float wsum[4];

    const int blk   = blockIdx.x;
    const int batch = blk / BPB;
    const int bb    = blk % BPB;
    const int tid   = threadIdx.x;
    const int wid   = tid >> 6;
    const int lane  = tid & 63;
    const int row0  = blk * ROWS;

    // ---- build K strip in LDS directly from C ----
    {
        const float4* c4g = (const float4*)(C + (size_t)row0 * MN);
        float4* k4l = (float4*)ldsK;
        for (int i = tid; i < ROWS * MN / 4; i += 256) {
            float4 c = c4g[i];
            float4 k;
            k.x = expf(-EPS_INV * c.x);
            k.y = expf(-EPS_INV * c.y);
            k.z = expf(-EPS_INV * c.z);
            k.w = expf(-EPS_INV * c.w);
            k4l[i] = k;
        }
    }
    __syncthreads();

    float*    partB = part   + (size_t)batch * BPB * MN;  // [bb][c]
    float*    svecB = svec_g + (size_t)batch * MN;
    unsigned* arrAB = arrA + (size_t)batch * ITERS * 64;
    unsigned* arrBB = arrB + (size_t)batch * ITERS * 64;
    const float inv = 1.0f / (float)MN;
    float rv[4];

    for (int t = 1; t <= ITERS; ++t) {
        // ---- r-phase: r[m] = inv / (K[m,:] . s_{t-1}); s_0 == 1 ----
        float4 v0, v1, v2, v3;
        if (t == 1) {
            v0 = v1 = v2 = v3 = make_float4(1.f, 1.f, 1.f, 1.f);
        } else {
            const float4* sv4 = (const float4*)vlds;
            v0 = sv4[lane]; v1 = sv4[64 + lane];
            v2 = sv4[128 + lane]; v3 = sv4[192 + lane];
        }
#pragma unroll
        for (int j = 0; j < 4; ++j) {
            const float4* l4 = (const float4*)(ldsK + (wid * 4 + j) * MN);
            float a = dot4(l4[lane], v0) + dot4(l4[64 + lane], v1)
                    + dot4(l4[128 + lane], v2) + dot4(l4[192 + lane], v3);
            a = wave_reduce(a);
            rv[j] = inv / a;
            if (lane == 0) rbuf[wid * 4 + j] = rv[j];
        }
        __syncthreads();  // rbuf ready; everyone done with vlds

        // ---- own-strip column partial: thread owns 4 contiguous cols ----
        const int c0 = tid * 4;
        float4 facc = make_float4(0.f, 0.f, 0.f, 0.f);
#pragma unroll
        for (int m = 0; m < ROWS; ++m) {
            float4 k4 = *(const float4*)(ldsK + m * MN + c0);
            float rm = rbuf[m];
            facc.x += k4.x * rm; facc.y += k4.y * rm;
            facc.z += k4.z * rm; facc.w += k4.w * rm;
        }
        float* ps = partB + (size_t)bb * MN + c0;
        st_f(ps + 0, facc.x); st_f(ps + 1, facc.y);
        st_f(ps + 2, facc.z); st_f(ps + 3, facc.w);
        __syncthreads();  // vmcnt(0): partial stores committed
        if (tid == 0)
            __hip_atomic_store(arrAB + (size_t)(t - 1) * 64 + bb, (unsigned)t,
                               __ATOMIC_RELAXED, __HIP_MEMORY_SCOPE_AGENT);

        // ---- hop A: wait for all 64 partials ----
        if (tid < 64) {
            const unsigned* at = arrAB + (size_t)(t - 1) * 64;
            while (!__all(ld_tag(at + lane) == (unsigned)t))
                __builtin_amdgcn_s_sleep(1);
        }
        __syncthreads();

        // ---- reduce own 16 columns: thread i -> col bb*16+(i>>4), chunk i&15 ----
        {
            const int cl  = tid >> 4;            // 0..15 local col
            const int col = bb * 16 + cl;
            const int j0  = (tid & 15) * 4;      // producer chunk
            float a = ld_f(partB + (size_t)(j0 + 0) * MN + col)
                    + ld_f(partB + (size_t)(j0 + 1) * MN + col)
                    + ld_f(partB + (size_t)(j0 + 2) * MN + col)
                    + ld_f(partB + (size_t)(j0 + 3) * MN + col);
            redsum[cl][tid & 15] = a;
        }
        __syncthreads();
        if (tid < 16) {
            float tot = 0.f;
#pragma unroll
            for (int k = 0; k < 16; ++k) tot += redsum[tid][k];
            st_f(svecB + bb * 16 + tid, inv / tot);
        }
        __syncthreads();  // vmcnt(0): s slice committed
        if (tid == 0)
            __hip_atomic_store(arrBB + (size_t)(t - 1) * 64 + bb, (unsigned)t,
                               __ATOMIC_RELAXED, __HIP_MEMORY_SCOPE_AGENT);

        // ---- hop B: wait for full s_t, stage into vlds ----
        if (tid < 64) {
            const unsigned* at = arrBB + (size_t)(t - 1) * 64;
            while (!__all(ld_tag(at + lane) == (unsigned)t))
                __builtin_amdgcn_s_sleep(1);
        }
        __syncthreads();
        for (int i = tid; i < MN; i += 256) vlds[i] = ld_f(svecB + i);
        __syncthreads();
    }

    // ---- finalize: P[row,:] = r[m]*K[m,:]*s ; dist via tagged partials ----
    float4 sv[4];
    {
        const float4* sv4 = (const float4*)vlds;  // s_40
        sv[0] = sv4[lane]; sv[1] = sv4[64 + lane];
        sv[2] = sv4[128 + lane]; sv[3] = sv4[192 + lane];
    }
    float dsum = 0.f;
#pragma unroll
    for (int j = 0; j < 4; ++j) {
        const int row = row0 + wid * 4 + j;
        const float4* l4 = (const float4*)(ldsK + (wid * 4 + j) * MN);
        const float4* c4 = (const float4*)(C + (size_t)row * MN);
        float4*       p4 = (float4*)(P + (size_t)row * MN);
        const float rj = rv[j];
#pragma unroll
        for (int c = 0; c < 4; ++c) {
            float4 k  = l4[c * 64 + lane];
            float4 cc = c4[c * 64 + lane];
            float4 pp;
            pp.x = rj * k.x * sv[c].x;
            pp.y = rj * k.y * sv[c].y;
            pp.z = rj * k.z * sv[c].z;
            pp.w = rj * k.w * sv[c].w;
            p4[c * 64 + lane] = pp;
            dsum += dot4(pp, cc);
        }
    }
    dsum = wave_reduce(dsum);
    if (lane == 0) wsum[wid] = dsum;
    __syncthreads();
    if (tid == 0) {
        float tot = wsum[0] + wsum[1] + wsum[2] + wsum[3];
        unsigned long long w = (0x5151ULL << 32) |
                               (unsigned long long)__float_as_uint(tot);
        __hip_atomic_store(dpart + blk, w, __ATOMIC_RELAXED, __HIP_MEMORY_SCOPE_AGENT);
    }
    if (bb == 0 && wid == 0) {  // batch leader sums 64 tagged partials
        unsigned long long w;
        for (;;) {
            w = __hip_atomic_load(dpart + (size_t)batch * 64 + lane,
                                  __ATOMIC_RELAXED, __HIP_MEMORY_SCOPE_AGENT);
            if (__all((unsigned)(w >> 32) == 0x5151u)) break;
            __builtin_amdgcn_s_sleep(1);
        }
        float v = wave_reduce(__uint_as_float((unsigned)w));
        if (lane == 0) dist[batch] = v;
    }
}

extern "C" void kernel_launch(void* const* d_in, const int* in_sizes, int n_in,
                              void* d_out, int out_size, void* d_ws, size_t ws_size,
                              hipStream_t stream) {
    const float* C = (const float*)d_in[0];
    const int B = in_sizes[0] / (MN * MN);  // 4

    // ws: part [B*64*MN f32] | svec [B*MN f32] | dpart [B*64 u64]
    //   | arrA [B*ITERS*64 u32] | arrB [B*ITERS*64 u32]
    float* part   = (float*)d_ws;
    float* svec_g = part + (size_t)B * BPB * MN;
    unsigned long long* dpart = (unsigned long long*)(svec_g + (size_t)B * MN);
    unsigned* arrA = (unsigned*)(dpart + (size_t)B * 64);
    unsigned* arrB = arrA + (size_t)B * ITERS * 64;

    float* dist = (float*)d_out;       // (B,)
    float* P    = (float*)d_out + B;   // (B, MN, MN)

    sink_all<<<B * BPB, 256, 0, stream>>>(C, part, svec_g, arrA, arrB, dpart, P, dist);
}